// Round 21
// baseline (112.664 us; speedup 1.0000x reference)
//
#include <hip/hip_runtime.h>
#include <hip/hip_bf16.h>

// Shapes: B=4, N=8192, C=256, H=4, D=64, P=64
#define NN 8192
#define BNC 8388608   // B*N*C

typedef unsigned short u16;
typedef unsigned int u32;
typedef __attribute__((ext_vector_type(8))) short bf16x8;
typedef __attribute__((ext_vector_type(4))) float f32x4;
typedef __attribute__((ext_vector_type(4))) float float4v;

__device__ __forceinline__ float bf2f(u16 u) {
    union { u32 i; float f; } c; c.i = ((u32)u) << 16; return c.f;
}
__device__ __forceinline__ u16 f2bf(float f) {
    union { float f; u32 i; } c; c.f = f;
    u32 x = c.i;
    u32 r = (x + 0x7fffu + ((x >> 16) & 1u)) >> 16;  // RNE
    return (u16)r;
}
__device__ __forceinline__ void gl16(const u16* g, u16* l) {
    __builtin_amdgcn_global_load_lds(
        (const __attribute__((address_space(1))) void*)g,
        (__attribute__((address_space(3))) void*)l, 16, 0, 0);
}

// ---------------- diagnostic fill ----------------
__global__ void fill_kernel(float* __restrict__ out, float val) {
    int base = (blockIdx.x * 256 + threadIdx.x) * 4;
    #pragma unroll
    for (int i = 0; i < 4; ++i) out[base + i] = val;
}

// ================= stage 1: zero + weights-only fp32->bf16 (600 blocks) =================
// blocks 0..335: convert Wq,Wk,Wo1,Ew (688,128 elements); 336..599: zero 67584 floats.
__global__ void zeroconv_kernel(const float* __restrict__ Wq, const float* __restrict__ Wk,
                                const float* __restrict__ Wo1, const float* __restrict__ Ew,
                                u16* __restrict__ Wqb, u16* __restrict__ Wkb,
                                u16* __restrict__ Wo1b, u16* __restrict__ Ewb,
                                float* __restrict__ zbase) {
    if (blockIdx.x >= 336) {
        int i = (blockIdx.x - 336) * 256 + threadIdx.x;
        if (i < 67584) zbase[i] = 0.f;
        return;
    }
    size_t e = ((size_t)blockIdx.x * 256 + threadIdx.x) * 8;
    const float* src; u16* dst;
    if (e < 65536)       { src = Wq  + e;            dst = Wqb  + e; }
    else if (e < 131072) { src = Wk  + (e - 65536);  dst = Wkb  + (e - 65536); }
    else if (e < 163840) { src = Wo1 + (e - 131072); dst = Wo1b + (e - 131072); }
    else                 { src = Ew  + (e - 163840); dst = Ewb  + (e - 163840); }
    float4v f0 = *(const float4v*)src, f1 = *(const float4v*)(src + 4);
    bf16x8 v;
    #pragma unroll
    for (int j = 0; j < 4; ++j) {
        v[j] = (short)f2bf(f0[j]); v[4 + j] = (short)f2bf(f1[j]);
    }
    *(bf16x8*)dst = v;
}

// ================= stage 2: Q/K GEMM (1024) || xE (256) || x->xb conv (4096) =================
// gemm: bx<1024: mt=bx&255, nt=(bx>>8)&1, z=bx>>9; A = fp32 (q or x), conv in staging.
// xe: bx in [1024,1280): reads x fp32, converts during transposed staging.
// xconv: bx in [1280,5376): copy x -> xb bf16.
__global__ __launch_bounds__(256) void qkxe_kernel(
    const float* __restrict__ qf, const float* __restrict__ x, u16* __restrict__ xb,
    const u16* __restrict__ Wqb, const u16* __restrict__ Wkb,
    u16* __restrict__ Qb, u16* __restrict__ Kb,
    float* __restrict__ nq2, float* __restrict__ nk2,
    const u16* __restrict__ Ewb, float* __restrict__ xE)
{
    __shared__ u16 sm[17408];
    const int t = threadIdx.x, lane = t & 63, w = t >> 6;
    const int fr = lane & 15, fk = (lane >> 4) * 8, r0 = (lane >> 4) * 4;

    if (blockIdx.x >= 1280) {
        // x -> xb bf16 copy
        size_t e = ((size_t)(blockIdx.x - 1280) * 256 + t) * 8;
        float4v f0 = *(const float4v*)(x + e), f1 = *(const float4v*)(x + e + 4);
        bf16x8 v;
        #pragma unroll
        for (int j = 0; j < 4; ++j) {
            v[j] = (short)f2bf(f0[j]); v[4 + j] = (short)f2bf(f1[j]);
        }
        *(bf16x8*)(xb + e) = v;
        return;
    }

    if (blockIdx.x < 1024) {
        u16* As = sm;            // [128][32]
        u16* Bs = sm + 4096;
        const int mt = blockIdx.x & 255, nt = (blockIdx.x >> 8) & 1, z = blockIdx.x >> 9;
        const float* Af = z ? x : qf;
        const u16* Bt = z ? Wkb : Wqb;
        u16* O = z ? Kb : Qb;
        float* dstn = z ? nk2 : nq2;
        const int wr = w >> 1, wc = w & 1;
        const int m0 = mt * 128, n0 = nt * 128;
        const int b = m0 >> 13;
        const int row0 = t >> 2, k80 = (t & 3) * 8;
        const int row1 = (256 + t) >> 2, k81 = ((256 + t) & 3) * 8;

        f32x4 acc[4][4];
        #pragma unroll
        for (int i = 0; i < 4; ++i)
            #pragma unroll
            for (int j = 0; j < 4; ++j) acc[i][j] = (f32x4){0.f, 0.f, 0.f, 0.f};

        for (int kt = 0; kt < 8; ++kt) {
            const int k0 = kt * 32;
            {
                const float* p0 = Af + (size_t)(m0 + row0) * 256 + k0 + k80;
                float4v f0 = *(const float4v*)p0, f1 = *(const float4v*)(p0 + 4);
                bf16x8 va;
                #pragma unroll
                for (int j = 0; j < 4; ++j) {
                    va[j] = (short)f2bf(f0[j]); va[4 + j] = (short)f2bf(f1[j]);
                }
                *(bf16x8*)&As[t * 8] = va;
                const float* p1 = Af + (size_t)(m0 + row1) * 256 + k0 + k81;
                float4v g0 = *(const float4v*)p1, g1 = *(const float4v*)(p1 + 4);
                bf16x8 vb2;
                #pragma unroll
                for (int j = 0; j < 4; ++j) {
                    vb2[j] = (short)f2bf(g0[j]); vb2[4 + j] = (short)f2bf(g1[j]);
                }
                *(bf16x8*)&As[(256 + t) * 8] = vb2;
            }
            gl16(Bt + (size_t)(n0 + row0) * 256 + k0 + k80, &Bs[t * 8]);
            gl16(Bt + (size_t)(n0 + row1) * 256 + k0 + k81, &Bs[(256 + t) * 8]);
            __syncthreads();
            bf16x8 a[4], bfr[4];
            #pragma unroll
            for (int fm = 0; fm < 4; ++fm)
                a[fm] = *(const bf16x8*)&As[(wr * 64 + fm * 16 + fr) * 32 + fk];
            #pragma unroll
            for (int fn = 0; fn < 4; ++fn)
                bfr[fn] = *(const bf16x8*)&Bs[(wc * 64 + fn * 16 + fr) * 32 + fk];
            #pragma unroll
            for (int fm = 0; fm < 4; ++fm)
                #pragma unroll
                for (int fn = 0; fn < 4; ++fn)
                    acc[fm][fn] = __builtin_amdgcn_mfma_f32_16x16x32_bf16(
                        a[fm], bfr[fn], acc[fm][fn], 0, 0, 0);
            __syncthreads();
        }

        #pragma unroll
        for (int fn = 0; fn < 4; ++fn) {
            int gcol = n0 + wc * 64 + fn * 16 + fr;
            float s = 0.f;
            #pragma unroll
            for (int fm = 0; fm < 4; ++fm) {
                #pragma unroll
                for (int r = 0; r < 4; ++r) {
                    size_t grow = (size_t)(m0 + wr * 64 + fm * 16 + r0 + r);
                    float v = acc[fm][fn][r];
                    O[grow * 256 + gcol] = f2bf(v);
                    s += v * v;
                }
            }
            s += __shfl_xor(s, 16);
            s += __shfl_xor(s, 32);
            if (lane < 16) atomicAdd(&dstn[b * 256 + gcol], s);
        }
    } else {
        u16 (*smA)[136] = (u16(*)[136])sm;
        u16 (*smB)[136] = (u16(*)[136])(sm + 8704);
        const int bx2 = blockIdx.x - 1024;
        const int bkq = bx2 >> 4, nc = bx2 & 15;
        const int b = bkq >> 2, kq = bkq & 3;

        f32x4 acc[4][4];
        #pragma unroll
        for (int i = 0; i < 4; ++i)
            #pragma unroll
            for (int j = 0; j < 4; ++j) acc[i][j] = (f32x4){0.f, 0.f, 0.f, 0.f};

        for (int it = 0; it < 4; ++it) {
            const int n0 = nc * 512 + it * 128;
            #pragma unroll
            for (int i = 0; i < 4; ++i) {
                int c = i * 256 + t, tok = c >> 3, kl = (c & 7) * 8;
                const int sw = tok ^ ((kl >> 3) << 3);
                const float* p = x + ((size_t)b * NN + n0 + tok) * 256 + kq * 64 + kl;
                float4v f0 = *(const float4v*)p, f1 = *(const float4v*)(p + 4);
                #pragma unroll
                for (int j = 0; j < 4; ++j) {
                    smA[kl + j][sw]     = f2bf(f0[j]);
                    smA[kl + 4 + j][sw] = f2bf(f1[j]);
                }
            }
            #pragma unroll
            for (int i = 0; i < 4; ++i) {
                int c = i * 256 + t, p = c >> 4, tk8 = (c & 15) * 8;
                *(bf16x8*)&smB[p][tk8] = *(const bf16x8*)(Ewb + (size_t)p * NN + n0 + tk8);
            }
            __syncthreads();
            bf16x8 a[4], bb[4];
            #pragma unroll
            for (int fm = 0; fm < 4; ++fm) {
                int row = fm * 16 + fr;
                a[fm] = *(const bf16x8*)&smA[row][(w * 32 + fk) ^ (((row >> 3) & 7) << 3)];
            }
            #pragma unroll
            for (int fn = 0; fn < 4; ++fn)
                bb[fn] = *(const bf16x8*)&smB[fn * 16 + fr][w * 32 + fk];
            #pragma unroll
            for (int fm = 0; fm < 4; ++fm)
                #pragma unroll
                for (int fn = 0; fn < 4; ++fn)
                    acc[fm][fn] = __builtin_amdgcn_mfma_f32_16x16x32_bf16(
                        a[fm], bb[fn], acc[fm][fn], 0, 0, 0);
            __syncthreads();
        }
        float* Cred = (float*)&smA[0][0];
        for (int ph = 0; ph < 4; ++ph) {
            if (w == ph) {
                #pragma unroll
                for (int fm = 0; fm < 4; ++fm)
                    #pragma unroll
                    for (int fn = 0; fn < 4; ++fn)
                        #pragma unroll
                        for (int r = 0; r < 4; ++r) {
                            int idx = (fm * 16 + r0 + r) * 64 + fn * 16 + fr;
                            if (ph == 0) Cred[idx] = acc[fm][fn][r];
                            else         Cred[idx] += acc[fm][fn][r];
                        }
            }
            __syncthreads();
        }
        float* dst = xE + (size_t)(b * 256 + kq * 64) * 64;
        #pragma unroll
        for (int i = 0; i < 16; ++i) atomicAdd(&dst[i * 256 + t], Cred[i * 256 + t]);
    }
}

// ================= stage 3: calog-MFMA (256 blks) || kvproj (512 blks) =================
__global__ __launch_bounds__(256) void calogkv_kernel(
    const u16* __restrict__ Qb, const u16* __restrict__ Kb, float* __restrict__ cpart,
    const float* __restrict__ Wk, const float* __restrict__ Wvsa,
    const float* __restrict__ xE, const float* __restrict__ Eb,
    float* __restrict__ kp, float* __restrict__ vp)
{
    __shared__ u16 sm[17408];
    const int t = threadIdx.x, lane = t & 63, w = t >> 6;
    const int fr = lane & 15, fk = (lane >> 4) * 8, r0 = (lane >> 4) * 4;

    if (blockIdx.x < 256) {
        u16 (*smA)[136] = (u16(*)[136])sm;
        u16 (*smB)[136] = (u16(*)[136])(sm + 8704);
        const int bh = blockIdx.x >> 4, nc = blockIdx.x & 15;
        const int b = bh >> 2, h = bh & 3;

        f32x4 acc[4][4];
        #pragma unroll
        for (int i = 0; i < 4; ++i)
            #pragma unroll
            for (int j = 0; j < 4; ++j) acc[i][j] = (f32x4){0.f, 0.f, 0.f, 0.f};

        for (int it = 0; it < 4; ++it) {
            const int n0 = nc * 512 + it * 128;
            #pragma unroll
            for (int i = 0; i < 4; ++i) {
                int c = i * 256 + t, tok = c >> 3, ch8 = (c & 7) * 8;
                const int sw = tok ^ ((ch8 >> 3) << 3);
                size_t g = ((size_t)b * NN + n0 + tok) * 256 + h * 64 + ch8;
                bf16x8 vq = *(const bf16x8*)(Qb + g);
                bf16x8 vk = *(const bf16x8*)(Kb + g);
                #pragma unroll
                for (int j = 0; j < 8; ++j) {
                    smA[ch8 + j][sw] = (u16)vq[j];
                    smB[ch8 + j][sw] = (u16)vk[j];
                }
            }
            __syncthreads();
            bf16x8 a[4], bb[4];
            #pragma unroll
            for (int fm = 0; fm < 4; ++fm) {
                int row = fm * 16 + fr;
                a[fm] = *(const bf16x8*)&smA[row][(w * 32 + fk) ^ (((row >> 3) & 7) << 3)];
            }
            #pragma unroll
            for (int fn = 0; fn < 4; ++fn) {
                int row = fn * 16 + fr;
                bb[fn] = *(const bf16x8*)&smB[row][(w * 32 + fk) ^ (((row >> 3) & 7) << 3)];
            }
            #pragma unroll
            for (int fm = 0; fm < 4; ++fm)
                #pragma unroll
                for (int fn = 0; fn < 4; ++fn)
                    acc[fm][fn] = __builtin_amdgcn_mfma_f32_16x16x32_bf16(
                        a[fm], bb[fn], acc[fm][fn], 0, 0, 0);
            __syncthreads();
        }
        float* Cred = (float*)&smA[0][0];
        for (int ph = 0; ph < 4; ++ph) {
            if (w == ph) {
                #pragma unroll
                for (int fm = 0; fm < 4; ++fm)
                    #pragma unroll
                    for (int fn = 0; fn < 4; ++fn)
                        #pragma unroll
                        for (int r = 0; r < 4; ++r) {
                            int idx = (fm * 16 + r0 + r) * 64 + fn * 16 + fr;
                            if (ph == 0) Cred[idx] = acc[fm][fn][r];
                            else         Cred[idx] += acc[fm][fn][r];
                        }
            }
            __syncthreads();
        }
        float* dst = cpart + (size_t)nc * 65536 + (size_t)bh * 4096;
        #pragma unroll
        for (int i = 0; i < 16; ++i) dst[i * 256 + t] = Cred[i * 256 + t];
    } else {
        const int idx = blockIdx.x - 256;
        const int z = idx >> 8, bc4 = idx & 255;
        const int b = bc4 >> 6, c = (bc4 & 63) * 4 + (t >> 6);
        const int p = t & 63;
        const float* W = z ? Wvsa : Wk;
        float* dst = z ? vp : kp;
        float s = 0.f;
        for (int k = 0; k < 256; ++k)
            s += W[c * 256 + k] * xE[(size_t)(b * 256 + k) * 64 + p];
        dst[(size_t)(b * 256 + c) * 64 + p] = s + Eb[p];
    }
}

// ================= stage 4: casoftmax (256 blks) || sa_mfma (512 blks) =================
__global__ __launch_bounds__(256) void smsa_kernel(
    const float* __restrict__ cpart, const float* __restrict__ nq2,
    const float* __restrict__ nk2, const float* __restrict__ temp,
    float* __restrict__ caprob,
    const u16* __restrict__ Qb, const float* __restrict__ kp,
    const float* __restrict__ vp, const float* __restrict__ temp2,
    u16* __restrict__ xsa)
{
    __shared__ char smem[49152];
    const int t = threadIdx.x;
    if (blockIdx.x < 256) {
        const int row = blockIdx.x * 4 + (t >> 6);
        const int e = t & 63;
        const int b = row >> 8, c = row & 255, h = c >> 6;
        const int i = row * 64 + e;
        float lg = cpart[i];
        #pragma unroll
        for (int nc = 1; nc < 16; ++nc) lg += cpart[(size_t)nc * 65536 + i];
        float nq = fmaxf(sqrtf(nq2[row]), 1e-12f);
        float nk = fmaxf(sqrtf(nk2[b * 256 + h * 64 + e]), 1e-12f);
        float v = lg / (nq * nk) * temp[h];
        float m = v;
        #pragma unroll
        for (int o = 32; o; o >>= 1) m = fmaxf(m, __shfl_xor(m, o));
        float ex = __expf(v - m);
        float s = ex;
        #pragma unroll
        for (int o = 32; o; o >>= 1) s += __shfl_xor(s, o);
        caprob[i] = ex / s;
        return;
    }
    u16* Qs = (u16*)smem;
    u16* KT = (u16*)(smem + 32768);
    u16* VT = (u16*)(smem + 40960);
    const int bx2 = blockIdx.x - 256;
    const int nc = bx2 & 31, bh = bx2 >> 5, b = bh >> 2, h = bh & 3;
    const int lane = t & 63, w = t >> 6;
    const int fr = lane & 15, fk = (lane >> 4) * 8, r0 = (lane >> 4) * 4;

    #pragma unroll
    for (int i = 0; i < 8; ++i) {
        int c = i * 256 + t, tok = c >> 3, ch8 = (c & 7) * 8;
        *(bf16x8*)&Qs[c * 8] =
            *(const bf16x8*)(Qb + ((size_t)b * NN + nc * 256 + tok) * 256 + h * 64 + ch8);
    }
    {
        const int d = t >> 2, p0 = (t & 3) * 16;
        const float rqv = 1.0f / fmaxf(sqrtf(nq2[b * 256 + h * 64 + d]), 1e-12f);
        const float t2 = temp2[h];
        const float* kr = kp + (size_t)(b * 256 + h * 64 + d) * 64 + p0;
        #pragma unroll
        for (int j = 0; j < 16; ++j)
            KT[(p0 + j) * 64 + d] = f2bf(kr[j] * rqv * t2);
    }
    {
        const float* vs = vp + (size_t)(b * 256 + h * 64) * 64;
        #pragma unroll
        for (int i = 0; i < 2; ++i) {
            int c = i * 256 + t;
            bf16x8 v;
            #pragma unroll
            for (int j = 0; j < 8; ++j) v[j] = (short)f2bf(vs[c * 8 + j]);
            *(bf16x8*)&VT[c * 8] = v;
        }
    }
    __syncthreads();

    f32x4 acc[4][4];
    #pragma unroll
    for (int i = 0; i < 4; ++i)
        #pragma unroll
        for (int j = 0; j < 4; ++j) acc[i][j] = (f32x4){0.f, 0.f, 0.f, 0.f};
    #pragma unroll
    for (int ks = 0; ks < 2; ++ks) {
        bf16x8 a[4], bb[4];
        #pragma unroll
        for (int fm = 0; fm < 4; ++fm)
            a[fm] = *(const bf16x8*)&Qs[(w * 64 + fm * 16 + fr) * 64 + ks * 32 + fk];
        #pragma unroll
        for (int fn = 0; fn < 4; ++fn)
            bb[fn] = *(const bf16x8*)&KT[(fn * 16 + fr) * 64 + ks * 32 + fk];
        #pragma unroll
        for (int fm = 0; fm < 4; ++fm)
            #pragma unroll
            for (int fn = 0; fn < 4; ++fn)
                acc[fm][fn] = __builtin_amdgcn_mfma_f32_16x16x32_bf16(
                    a[fm], bb[fn], acc[fm][fn], 0, 0, 0);
    }
    __syncthreads();

    u16* Pw = Qs + w * 4096;
    #pragma unroll
    for (int fm = 0; fm < 4; ++fm) {
        #pragma unroll
        for (int r = 0; r < 4; ++r) {
            float m = fmaxf(fmaxf(acc[fm][0][r], acc[fm][1][r]),
                            fmaxf(acc[fm][2][r], acc[fm][3][r]));
            m = fmaxf(m, __shfl_xor(m, 1));
            m = fmaxf(m, __shfl_xor(m, 2));
            m = fmaxf(m, __shfl_xor(m, 4));
            m = fmaxf(m, __shfl_xor(m, 8));
            float e0 = __expf(acc[fm][0][r] - m), e1 = __expf(acc[fm][1][r] - m);
            float e2 = __expf(acc[fm][2][r] - m), e3 = __expf(acc[fm][3][r] - m);
            float s = e0 + e1 + e2 + e3;
            s += __shfl_xor(s, 1); s += __shfl_xor(s, 2);
            s += __shfl_xor(s, 4); s += __shfl_xor(s, 8);
            float rs = 1.0f / s;
            int row = fm * 16 + r0 + r;
            Pw[row * 64 +  0 + fr] = f2bf(e0 * rs);
            Pw[row * 64 + 16 + fr] = f2bf(e1 * rs);
            Pw[row * 64 + 32 + fr] = f2bf(e2 * rs);
            Pw[row * 64 + 48 + fr] = f2bf(e3 * rs);
        }
    }

    f32x4 acc2[4][4];
    #pragma unroll
    for (int i = 0; i < 4; ++i)
        #pragma unroll
        for (int j = 0; j < 4; ++j) acc2[i][j] = (f32x4){0.f, 0.f, 0.f, 0.f};
    #pragma unroll
    for (int ks = 0; ks < 2; ++ks) {
        bf16x8 a[4], bb[4];
        #pragma unroll
        for (int fm = 0; fm < 4; ++fm)
            a[fm] = *(const bf16x8*)&Pw[(fm * 16 + fr) * 64 + ks * 32 + fk];
        #pragma unroll
        for (int fn = 0; fn < 4; ++fn)
            bb[fn] = *(const bf16x8*)&VT[(fn * 16 + fr) * 64 + ks * 32 + fk];
        #pragma unroll
        for (int fm = 0; fm < 4; ++fm)
            #pragma unroll
            for (int fn = 0; fn < 4; ++fn)
                acc2[fm][fn] = __builtin_amdgcn_mfma_f32_16x16x32_bf16(
                    a[fm], bb[fn], acc2[fm][fn], 0, 0, 0);
    }
    __syncthreads();

    u16* X2 = Qs;
    #pragma unroll
    for (int fm = 0; fm < 4; ++fm)
        #pragma unroll
        for (int fn = 0; fn < 4; ++fn)
            #pragma unroll
            for (int r = 0; r < 4; ++r)
                X2[(w * 64 + fm * 16 + r0 + r) * 64 + fn * 16 + fr] = f2bf(acc2[fm][fn][r]);
    __syncthreads();

    {
        const int d = t >> 2, cq = (t & 3) * 64;
        u16* orow = xsa + ((size_t)b * NN + d * 128 + h * 32 + nc) * 256 + cq;
        #pragma unroll
        for (int i = 0; i < 8; ++i) {
            bf16x8 v;
            #pragma unroll
            for (int j = 0; j < 8; ++j) v[j] = (short)X2[(cq + i * 8 + j) * 64 + d];
            *(bf16x8*)&orow[i * 8] = v;
        }
    }
}

// ---- shared GEMM body for out halves (R15 verified form) ----
__device__ __forceinline__ void out_gemm_body(
    const u16* __restrict__ A, const u16* __restrict__ Bt,
    const float* __restrict__ bias, int outoff, int m0,
    float* __restrict__ out, u16* As, u16* Bs, int t)
{
    const int lane = t & 63, w = t >> 6;
    const int wr = w >> 1, wc = w & 1;
    const int fr = lane & 15, fk = (lane >> 4) * 8, r0 = (lane >> 4) * 4;
    const int row0 = t >> 2, k80 = (t & 3) * 8;
    const int row1 = (256 + t) >> 2, k81 = ((256 + t) & 3) * 8;

    f32x4 acc[4][4];
    #pragma unroll
    for (int i = 0; i < 4; ++i)
        #pragma unroll
        for (int j = 0; j < 4; ++j) acc[i][j] = (f32x4){0.f, 0.f, 0.f, 0.f};

    for (int kt = 0; kt < 8; ++kt) {
        const int k0 = kt * 32;
        gl16(A  + (size_t)(m0 + row0) * 256 + k0 + k80, &As[t * 8]);
        gl16(A  + (size_t)(m0 + row1) * 256 + k0 + k81, &As[(256 + t) * 8]);
        gl16(Bt + (size_t)row0 * 256 + k0 + k80, &Bs[t * 8]);
        gl16(Bt + (size_t)row1 * 256 + k0 + k81, &Bs[(256 + t) * 8]);
        __syncthreads();
        bf16x8 a[4], bfr[4];
        #pragma unroll
        for (int fm = 0; fm < 4; ++fm)
            a[fm] = *(const bf16x8*)&As[(wr * 64 + fm * 16 + fr) * 32 + fk];
        #pragma unroll
        for (int fn = 0; fn < 4; ++fn)
            bfr[fn] = *(const bf16x8*)&Bs[(wc * 64 + fn * 16 + fr) * 32 + fk];
        #pragma unroll
        for (int fm = 0; fm < 4; ++fm)
            #pragma unroll
            for (int fn = 0; fn < 4; ++fn)
                acc[fm][fn] = __builtin_amdgcn_mfma_f32_16x16x32_bf16(
                    a[fm], bfr[fn], acc[fm][fn], 0, 0, 0);
        __syncthreads();
    }

    #pragma unroll
    for (int fm = 0; fm < 4; ++fm)
        #pragma unroll
        for (int fn = 0; fn < 4; ++fn) {
            int gcol = wc * 64 + fn * 16 + fr;
            #pragma unroll
            for (int r = 0; r < 4; ++r) {
                size_t grow = (size_t)(m0 + wr * 64 + fm * 16 + r0 + r);
                out[grow * 256 + outoff + gcol] = acc[fm][fn][r] + bias[gcol];
            }
        }
}

// ================= stage 5: mw2eff (512 blks) || outSA (256 blks) =================
__global__ __launch_bounds__(256) void mwout_kernel(
    const float* __restrict__ caprob, const float* __restrict__ Wo2,
    const float* __restrict__ Wvca, u16* __restrict__ W2effb,
    const u16* __restrict__ xsa, const u16* __restrict__ Wo1b,
    const float* __restrict__ bo1, float* __restrict__ out)
{
    __shared__ u16 sm[8192];
    const int t = threadIdx.x;
    if (blockIdx.x < 512) {
        float* Ml = (float*)sm;
        const int bj = blockIdx.x;
        const int b = bj >> 7, j = bj & 127;
        const int h = t >> 6, e = t & 63;
        float s = 0.f;
        #pragma unroll 8
        for (int d = 0; d < 64; ++d)
            s += Wo2[j * 256 + h * 64 + d] * caprob[(size_t)(b * 256 + h * 64 + d) * 64 + e];
        Ml[t] = s;
        __syncthreads();
        float s2 = 0.f;
        for (int c = 0; c < 256; ++c) s2 += Ml[c] * Wvca[c * 256 + t];
        W2effb[(size_t)bj * 256 + t] = f2bf(s2);
        return;
    }
    const int m0 = (blockIdx.x - 512) * 128;
    out_gemm_body(xsa, Wo1b, bo1, 0, m0, out, sm, sm + 4096, t);
}

// ================= stage 6: outCA (256 blks) =================
__global__ __launch_bounds__(256) void outca_kernel(
    const u16* __restrict__ xb, const u16* __restrict__ W2effb,
    const float* __restrict__ bo2, float* __restrict__ out)
{
    __shared__ u16 sm[8192];
    const int t = threadIdx.x;
    const int m0 = blockIdx.x * 128;
    const u16* Bt = W2effb + (size_t)(blockIdx.x >> 6) * 128 * 256;
    out_gemm_body(xb, Bt, bo2, 128, m0, out, sm, sm + 4096, t);
}

extern "C" void kernel_launch(void* const* d_in, const int* in_sizes, int n_in,
                              void* d_out, int out_size, void* d_ws, size_t ws_size,
                              hipStream_t stream) {
    float* out = (float*)d_out;

    static const int expect[14] = {8388608, 8388608, 65536, 65536, 65536, 65536,
                                   524288, 64, 4, 4, 32768, 128, 32768, 128};
    bool ok = (n_in == 14) && (out_size == 8388608);
    if (ok) for (int i = 0; i < 14; ++i) ok = ok && (in_sizes[i] == expect[i]);
    if (!ok) {
        fill_kernel<<<dim3(8192), 256, 0, stream>>>(out, 3000.0f);
        return;
    }
    if (ws_size < 80000000u) {
        fill_kernel<<<dim3(8192), 256, 0, stream>>>(out, 1000.0f);
        return;
    }

    const float* x    = (const float*)d_in[0];
    const float* q    = (const float*)d_in[1];
    const float* Wq   = (const float*)d_in[2];
    const float* Wk   = (const float*)d_in[3];
    const float* Wvca = (const float*)d_in[4];
    const float* Wvsa = (const float*)d_in[5];
    const float* Ew   = (const float*)d_in[6];
    const float* Eb   = (const float*)d_in[7];
    const float* temp = (const float*)d_in[8];
    const float* temp2= (const float*)d_in[9];
    const float* Wo1  = (const float*)d_in[10];
    const float* bo1  = (const float*)d_in[11];
    const float* Wo2  = (const float*)d_in[12];
    const float* bo2  = (const float*)d_in[13];

    u16* Qb   = (u16*)d_ws;
    u16* Kb   = Qb + (size_t)BNC;        // reused as xsa after calog (stream-ordered)
    u16* xb   = Kb + (size_t)BNC;
    u16* Wqb  = xb + (size_t)BNC;        // 65536
    u16* Wkb  = Wqb + 65536;             // 65536
    u16* Wo1b = Wkb + 65536;             // 32768
    u16* Ewb  = Wo1b + 32768;            // 524288
    u16* W2effb = Ewb + 524288;          // 131072
    u16* xsa  = Kb;
    float* fs    = (float*)(W2effb + 131072);
    float* nq2   = fs;                   // 1024
    float* nk2   = nq2 + 1024;           // 1024
    float* xE    = nk2 + 1024;           // 65536
    float* kp    = xE + 65536;           // 65536
    float* vp    = kp + 65536;           // 65536
    float* caprob= vp + 65536;           // 65536
    float* cpart = caprob + 65536;       // 1048576 (16 x 65536)

    zeroconv_kernel<<<dim3(600), 256, 0, stream>>>(Wq, Wk, Wo1, Ew,
                                                   Wqb, Wkb, Wo1b, Ewb, nq2);
    qkxe_kernel<<<dim3(5376), 256, 0, stream>>>(q, x, xb, Wqb, Wkb, Qb, Kb, nq2, nk2,
                                                Ewb, xE);
    calogkv_kernel<<<dim3(768), 256, 0, stream>>>(Qb, Kb, cpart, Wk, Wvsa, xE, Eb, kp, vp);
    smsa_kernel<<<dim3(768), 256, 0, stream>>>(cpart, nq2, nk2, temp, caprob,
                                               Qb, kp, vp, temp2, xsa);
    mwout_kernel<<<dim3(768), 256, 0, stream>>>(caprob, Wo2, Wvca, W2effb,
                                                xsa, Wo1b, bo1, out);
    outca_kernel<<<dim3(256), 256, 0, stream>>>(xb, W2effb, bo2, out);
}

// Round 22
// 105.351 us; speedup vs baseline: 1.0694x; 1.0694x over previous
//
#include <hip/hip_runtime.h>
#include <hip/hip_bf16.h>

// Shapes: B=4, N=8192, C=256, H=4, D=64, P=64
#define NN 8192
#define BNC 8388608   // B*N*C

typedef unsigned short u16;
typedef unsigned int u32;
typedef __attribute__((ext_vector_type(8))) short bf16x8;
typedef __attribute__((ext_vector_type(4))) float f32x4;
typedef __attribute__((ext_vector_type(4))) float float4v;

__device__ __forceinline__ float bf2f(u16 u) {
    union { u32 i; float f; } c; c.i = ((u32)u) << 16; return c.f;
}
__device__ __forceinline__ u16 f2bf(float f) {
    union { float f; u32 i; } c; c.f = f;
    u32 x = c.i;
    u32 r = (x + 0x7fffu + ((x >> 16) & 1u)) >> 16;  // RNE
    return (u16)r;
}
__device__ __forceinline__ void gl16(const u16* g, u16* l) {
    __builtin_amdgcn_global_load_lds(
        (const __attribute__((address_space(1))) void*)g,
        (__attribute__((address_space(3))) void*)l, 16, 0, 0);
}

// ---------------- diagnostic fill ----------------
__global__ void fill_kernel(float* __restrict__ out, float val) {
    int base = (blockIdx.x * 256 + threadIdx.x) * 4;
    #pragma unroll
    for (int i = 0; i < 4; ++i) out[base + i] = val;
}

// ================= stage 1: fused zero + bulk fp32->bf16 conversion =================
__global__ void zeroconv_kernel(const float* __restrict__ x,
                                const float* __restrict__ Wq, const float* __restrict__ Wk,
                                const float* __restrict__ Wo1, const float* __restrict__ Ew,
                                u16* __restrict__ xb,
                                u16* __restrict__ Wqb, u16* __restrict__ Wkb,
                                u16* __restrict__ Wo1b, u16* __restrict__ Ewb,
                                float* __restrict__ zbase) {
    if (blockIdx.x >= 4432) {
        int i = (blockIdx.x - 4432) * 256 + threadIdx.x;
        if (i < 67584) zbase[i] = 0.f;
        return;
    }
    size_t e = ((size_t)blockIdx.x * 256 + threadIdx.x) * 8;
    const float* src; u16* dst;
    if (e < 8388608)      { src = x   + e;             dst = xb   + e; }
    else if (e < 8454144) { src = Wq  + (e - 8388608); dst = Wqb  + (e - 8388608); }
    else if (e < 8519680) { src = Wk  + (e - 8454144); dst = Wkb  + (e - 8454144); }
    else if (e < 8552448) { src = Wo1 + (e - 8519680); dst = Wo1b + (e - 8519680); }
    else                  { src = Ew  + (e - 8552448); dst = Ewb  + (e - 8552448); }
    float4v f0 = *(const float4v*)src, f1 = *(const float4v*)(src + 4);
    bf16x8 v;
    #pragma unroll
    for (int j = 0; j < 4; ++j) {
        v[j] = (short)f2bf(f0[j]); v[4 + j] = (short)f2bf(f1[j]);
    }
    *(bf16x8*)dst = v;
}

// ================= stage 2: Q/K GEMM (1024 blks) || xE-MFMA (256 blks) =================
__global__ __launch_bounds__(256) void qkxe_kernel(
    const float* __restrict__ qf, const u16* __restrict__ xb,
    const u16* __restrict__ Wqb, const u16* __restrict__ Wkb,
    u16* __restrict__ Qb, u16* __restrict__ Kb,
    float* __restrict__ nq2, float* __restrict__ nk2,
    const u16* __restrict__ Ewb, float* __restrict__ xE)
{
    __shared__ u16 sm[17408];
    const int t = threadIdx.x, lane = t & 63, w = t >> 6;
    const int fr = lane & 15, fk = (lane >> 4) * 8, r0 = (lane >> 4) * 4;

    if (blockIdx.x < 1024) {
        u16* As = sm;            // [128][32]
        u16* Bs = sm + 4096;
        const int mt = blockIdx.x & 255, nt = (blockIdx.x >> 8) & 1, z = blockIdx.x >> 9;
        const u16* Bt = z ? Wkb : Wqb;
        u16* O = z ? Kb : Qb;
        float* dstn = z ? nk2 : nq2;
        const int wr = w >> 1, wc = w & 1;
        const int m0 = mt * 128, n0 = nt * 128;
        const int b = m0 >> 13;
        const int row0 = t >> 2, k80 = (t & 3) * 8;
        const int row1 = (256 + t) >> 2, k81 = ((256 + t) & 3) * 8;

        f32x4 acc[4][4];
        #pragma unroll
        for (int i = 0; i < 4; ++i)
            #pragma unroll
            for (int j = 0; j < 4; ++j) acc[i][j] = (f32x4){0.f, 0.f, 0.f, 0.f};

        for (int kt = 0; kt < 8; ++kt) {
            const int k0 = kt * 32;
            if (z == 0) {
                const float* p0 = qf + (size_t)(m0 + row0) * 256 + k0 + k80;
                float4v f0 = *(const float4v*)p0, f1 = *(const float4v*)(p0 + 4);
                bf16x8 va;
                #pragma unroll
                for (int j = 0; j < 4; ++j) {
                    va[j] = (short)f2bf(f0[j]); va[4 + j] = (short)f2bf(f1[j]);
                }
                *(bf16x8*)&As[t * 8] = va;
                const float* p1 = qf + (size_t)(m0 + row1) * 256 + k0 + k81;
                float4v g0 = *(const float4v*)p1, g1 = *(const float4v*)(p1 + 4);
                bf16x8 vb2;
                #pragma unroll
                for (int j = 0; j < 4; ++j) {
                    vb2[j] = (short)f2bf(g0[j]); vb2[4 + j] = (short)f2bf(g1[j]);
                }
                *(bf16x8*)&As[(256 + t) * 8] = vb2;
            } else {
                gl16(xb + (size_t)(m0 + row0) * 256 + k0 + k80, &As[t * 8]);
                gl16(xb + (size_t)(m0 + row1) * 256 + k0 + k81, &As[(256 + t) * 8]);
            }
            gl16(Bt + (size_t)(n0 + row0) * 256 + k0 + k80, &Bs[t * 8]);
            gl16(Bt + (size_t)(n0 + row1) * 256 + k0 + k81, &Bs[(256 + t) * 8]);
            __syncthreads();
            bf16x8 a[4], bfr[4];
            #pragma unroll
            for (int fm = 0; fm < 4; ++fm)
                a[fm] = *(const bf16x8*)&As[(wr * 64 + fm * 16 + fr) * 32 + fk];
            #pragma unroll
            for (int fn = 0; fn < 4; ++fn)
                bfr[fn] = *(const bf16x8*)&Bs[(wc * 64 + fn * 16 + fr) * 32 + fk];
            #pragma unroll
            for (int fm = 0; fm < 4; ++fm)
                #pragma unroll
                for (int fn = 0; fn < 4; ++fn)
                    acc[fm][fn] = __builtin_amdgcn_mfma_f32_16x16x32_bf16(
                        a[fm], bfr[fn], acc[fm][fn], 0, 0, 0);
            __syncthreads();
        }

        #pragma unroll
        for (int fn = 0; fn < 4; ++fn) {
            int gcol = n0 + wc * 64 + fn * 16 + fr;
            float s = 0.f;
            #pragma unroll
            for (int fm = 0; fm < 4; ++fm) {
                #pragma unroll
                for (int r = 0; r < 4; ++r) {
                    size_t grow = (size_t)(m0 + wr * 64 + fm * 16 + r0 + r);
                    float v = acc[fm][fn][r];
                    O[grow * 256 + gcol] = f2bf(v);
                    s += v * v;
                }
            }
            s += __shfl_xor(s, 16);
            s += __shfl_xor(s, 32);
            if (lane < 16) atomicAdd(&dstn[b * 256 + gcol], s);
        }
    } else {
        u16 (*smA)[136] = (u16(*)[136])sm;
        u16 (*smB)[136] = (u16(*)[136])(sm + 8704);
        const int bx2 = blockIdx.x - 1024;
        const int bkq = bx2 >> 4, nc = bx2 & 15;
        const int b = bkq >> 2, kq = bkq & 3;

        f32x4 acc[4][4];
        #pragma unroll
        for (int i = 0; i < 4; ++i)
            #pragma unroll
            for (int j = 0; j < 4; ++j) acc[i][j] = (f32x4){0.f, 0.f, 0.f, 0.f};

        for (int it = 0; it < 4; ++it) {
            const int n0 = nc * 512 + it * 128;
            #pragma unroll
            for (int i = 0; i < 4; ++i) {
                int c = i * 256 + t, tok = c >> 3, kl = (c & 7) * 8;
                const int sw = tok ^ ((kl >> 3) << 3);
                bf16x8 v = *(const bf16x8*)(xb + ((size_t)b * NN + n0 + tok) * 256 + kq * 64 + kl);
                #pragma unroll
                for (int j = 0; j < 8; ++j) smA[kl + j][sw] = (u16)v[j];
            }
            #pragma unroll
            for (int i = 0; i < 4; ++i) {
                int c = i * 256 + t, p = c >> 4, tk8 = (c & 15) * 8;
                *(bf16x8*)&smB[p][tk8] = *(const bf16x8*)(Ewb + (size_t)p * NN + n0 + tk8);
            }
            __syncthreads();
            bf16x8 a[4], bb[4];
            #pragma unroll
            for (int fm = 0; fm < 4; ++fm) {
                int row = fm * 16 + fr;
                a[fm] = *(const bf16x8*)&smA[row][(w * 32 + fk) ^ (((row >> 3) & 7) << 3)];
            }
            #pragma unroll
            for (int fn = 0; fn < 4; ++fn)
                bb[fn] = *(const bf16x8*)&smB[fn * 16 + fr][w * 32 + fk];
            #pragma unroll
            for (int fm = 0; fm < 4; ++fm)
                #pragma unroll
                for (int fn = 0; fn < 4; ++fn)
                    acc[fm][fn] = __builtin_amdgcn_mfma_f32_16x16x32_bf16(
                        a[fm], bb[fn], acc[fm][fn], 0, 0, 0);
            __syncthreads();
        }
        float* Cred = (float*)&smA[0][0];
        for (int ph = 0; ph < 4; ++ph) {
            if (w == ph) {
                #pragma unroll
                for (int fm = 0; fm < 4; ++fm)
                    #pragma unroll
                    for (int fn = 0; fn < 4; ++fn)
                        #pragma unroll
                        for (int r = 0; r < 4; ++r) {
                            int idx = (fm * 16 + r0 + r) * 64 + fn * 16 + fr;
                            if (ph == 0) Cred[idx] = acc[fm][fn][r];
                            else         Cred[idx] += acc[fm][fn][r];
                        }
            }
            __syncthreads();
        }
        float* dst = xE + (size_t)(b * 256 + kq * 64) * 64;
        #pragma unroll
        for (int i = 0; i < 16; ++i) atomicAdd(&dst[i * 256 + t], Cred[i * 256 + t]);
    }
}

// ================= stage 3: calog-MFMA (256 blks) || kvproj (512 blks) =================
__global__ __launch_bounds__(256) void calogkv_kernel(
    const u16* __restrict__ Qb, const u16* __restrict__ Kb, float* __restrict__ cpart,
    const float* __restrict__ Wk, const float* __restrict__ Wvsa,
    const float* __restrict__ xE, const float* __restrict__ Eb,
    float* __restrict__ kp, float* __restrict__ vp)
{
    __shared__ u16 sm[17408];
    const int t = threadIdx.x, lane = t & 63, w = t >> 6;
    const int fr = lane & 15, fk = (lane >> 4) * 8, r0 = (lane >> 4) * 4;

    if (blockIdx.x < 256) {
        u16 (*smA)[136] = (u16(*)[136])sm;
        u16 (*smB)[136] = (u16(*)[136])(sm + 8704);
        const int bh = blockIdx.x >> 4, nc = blockIdx.x & 15;
        const int b = bh >> 2, h = bh & 3;

        f32x4 acc[4][4];
        #pragma unroll
        for (int i = 0; i < 4; ++i)
            #pragma unroll
            for (int j = 0; j < 4; ++j) acc[i][j] = (f32x4){0.f, 0.f, 0.f, 0.f};

        for (int it = 0; it < 4; ++it) {
            const int n0 = nc * 512 + it * 128;
            #pragma unroll
            for (int i = 0; i < 4; ++i) {
                int c = i * 256 + t, tok = c >> 3, ch8 = (c & 7) * 8;
                const int sw = tok ^ ((ch8 >> 3) << 3);
                size_t g = ((size_t)b * NN + n0 + tok) * 256 + h * 64 + ch8;
                bf16x8 vq = *(const bf16x8*)(Qb + g);
                bf16x8 vk = *(const bf16x8*)(Kb + g);
                #pragma unroll
                for (int j = 0; j < 8; ++j) {
                    smA[ch8 + j][sw] = (u16)vq[j];
                    smB[ch8 + j][sw] = (u16)vk[j];
                }
            }
            __syncthreads();
            bf16x8 a[4], bb[4];
            #pragma unroll
            for (int fm = 0; fm < 4; ++fm) {
                int row = fm * 16 + fr;
                a[fm] = *(const bf16x8*)&smA[row][(w * 32 + fk) ^ (((row >> 3) & 7) << 3)];
            }
            #pragma unroll
            for (int fn = 0; fn < 4; ++fn) {
                int row = fn * 16 + fr;
                bb[fn] = *(const bf16x8*)&smB[row][(w * 32 + fk) ^ (((row >> 3) & 7) << 3)];
            }
            #pragma unroll
            for (int fm = 0; fm < 4; ++fm)
                #pragma unroll
                for (int fn = 0; fn < 4; ++fn)
                    acc[fm][fn] = __builtin_amdgcn_mfma_f32_16x16x32_bf16(
                        a[fm], bb[fn], acc[fm][fn], 0, 0, 0);
            __syncthreads();
        }
        float* Cred = (float*)&smA[0][0];
        for (int ph = 0; ph < 4; ++ph) {
            if (w == ph) {
                #pragma unroll
                for (int fm = 0; fm < 4; ++fm)
                    #pragma unroll
                    for (int fn = 0; fn < 4; ++fn)
                        #pragma unroll
                        for (int r = 0; r < 4; ++r) {
                            int idx = (fm * 16 + r0 + r) * 64 + fn * 16 + fr;
                            if (ph == 0) Cred[idx] = acc[fm][fn][r];
                            else         Cred[idx] += acc[fm][fn][r];
                        }
            }
            __syncthreads();
        }
        float* dst = cpart + (size_t)nc * 65536 + (size_t)bh * 4096;
        #pragma unroll
        for (int i = 0; i < 16; ++i) dst[i * 256 + t] = Cred[i * 256 + t];
    } else {
        const int idx = blockIdx.x - 256;
        const int z = idx >> 8, bc4 = idx & 255;
        const int b = bc4 >> 6, c = (bc4 & 63) * 4 + (t >> 6);
        const int p = t & 63;
        const float* W = z ? Wvsa : Wk;
        float* dst = z ? vp : kp;
        float s = 0.f;
        for (int k = 0; k < 256; ++k)
            s += W[c * 256 + k] * xE[(size_t)(b * 256 + k) * 64 + p];
        dst[(size_t)(b * 256 + c) * 64 + p] = s + Eb[p];
    }
}

// ================= stage 4: casoftmax (256 blks) || sa_mfma (512 blks) =================
__global__ __launch_bounds__(256) void smsa_kernel(
    const float* __restrict__ cpart, const float* __restrict__ nq2,
    const float* __restrict__ nk2, const float* __restrict__ temp,
    float* __restrict__ caprob,
    const u16* __restrict__ Qb, const float* __restrict__ kp,
    const float* __restrict__ vp, const float* __restrict__ temp2,
    u16* __restrict__ xsa)
{
    __shared__ char smem[49152];
    const int t = threadIdx.x;
    if (blockIdx.x < 256) {
        const int row = blockIdx.x * 4 + (t >> 6);
        const int e = t & 63;
        const int b = row >> 8, c = row & 255, h = c >> 6;
        const int i = row * 64 + e;
        float lg = cpart[i];
        #pragma unroll
        for (int nc = 1; nc < 16; ++nc) lg += cpart[(size_t)nc * 65536 + i];
        float nq = fmaxf(sqrtf(nq2[row]), 1e-12f);
        float nk = fmaxf(sqrtf(nk2[b * 256 + h * 64 + e]), 1e-12f);
        float v = lg / (nq * nk) * temp[h];
        float m = v;
        #pragma unroll
        for (int o = 32; o; o >>= 1) m = fmaxf(m, __shfl_xor(m, o));
        float ex = __expf(v - m);
        float s = ex;
        #pragma unroll
        for (int o = 32; o; o >>= 1) s += __shfl_xor(s, o);
        caprob[i] = ex / s;
        return;
    }
    u16* Qs = (u16*)smem;
    u16* KT = (u16*)(smem + 32768);
    u16* VT = (u16*)(smem + 40960);
    const int bx2 = blockIdx.x - 256;
    const int nc = bx2 & 31, bh = bx2 >> 5, b = bh >> 2, h = bh & 3;
    const int lane = t & 63, w = t >> 6;
    const int fr = lane & 15, fk = (lane >> 4) * 8, r0 = (lane >> 4) * 4;

    #pragma unroll
    for (int i = 0; i < 8; ++i) {
        int c = i * 256 + t, tok = c >> 3, ch8 = (c & 7) * 8;
        *(bf16x8*)&Qs[c * 8] =
            *(const bf16x8*)(Qb + ((size_t)b * NN + nc * 256 + tok) * 256 + h * 64 + ch8);
    }
    {
        const int d = t >> 2, p0 = (t & 3) * 16;
        const float rqv = 1.0f / fmaxf(sqrtf(nq2[b * 256 + h * 64 + d]), 1e-12f);
        const float t2 = temp2[h];
        const float* kr = kp + (size_t)(b * 256 + h * 64 + d) * 64 + p0;
        #pragma unroll
        for (int j = 0; j < 16; ++j)
            KT[(p0 + j) * 64 + d] = f2bf(kr[j] * rqv * t2);
    }
    {
        const float* vs = vp + (size_t)(b * 256 + h * 64) * 64;
        #pragma unroll
        for (int i = 0; i < 2; ++i) {
            int c = i * 256 + t;
            bf16x8 v;
            #pragma unroll
            for (int j = 0; j < 8; ++j) v[j] = (short)f2bf(vs[c * 8 + j]);
            *(bf16x8*)&VT[c * 8] = v;
        }
    }
    __syncthreads();

    f32x4 acc[4][4];
    #pragma unroll
    for (int i = 0; i < 4; ++i)
        #pragma unroll
        for (int j = 0; j < 4; ++j) acc[i][j] = (f32x4){0.f, 0.f, 0.f, 0.f};
    #pragma unroll
    for (int ks = 0; ks < 2; ++ks) {
        bf16x8 a[4], bb[4];
        #pragma unroll
        for (int fm = 0; fm < 4; ++fm)
            a[fm] = *(const bf16x8*)&Qs[(w * 64 + fm * 16 + fr) * 64 + ks * 32 + fk];
        #pragma unroll
        for (int fn = 0; fn < 4; ++fn)
            bb[fn] = *(const bf16x8*)&KT[(fn * 16 + fr) * 64 + ks * 32 + fk];
        #pragma unroll
        for (int fm = 0; fm < 4; ++fm)
            #pragma unroll
            for (int fn = 0; fn < 4; ++fn)
                acc[fm][fn] = __builtin_amdgcn_mfma_f32_16x16x32_bf16(
                    a[fm], bb[fn], acc[fm][fn], 0, 0, 0);
    }
    __syncthreads();

    u16* Pw = Qs + w * 4096;
    #pragma unroll
    for (int fm = 0; fm < 4; ++fm) {
        #pragma unroll
        for (int r = 0; r < 4; ++r) {
            float m = fmaxf(fmaxf(acc[fm][0][r], acc[fm][1][r]),
                            fmaxf(acc[fm][2][r], acc[fm][3][r]));
            m = fmaxf(m, __shfl_xor(m, 1));
            m = fmaxf(m, __shfl_xor(m, 2));
            m = fmaxf(m, __shfl_xor(m, 4));
            m = fmaxf(m, __shfl_xor(m, 8));
            float e0 = __expf(acc[fm][0][r] - m), e1 = __expf(acc[fm][1][r] - m);
            float e2 = __expf(acc[fm][2][r] - m), e3 = __expf(acc[fm][3][r] - m);
            float s = e0 + e1 + e2 + e3;
            s += __shfl_xor(s, 1); s += __shfl_xor(s, 2);
            s += __shfl_xor(s, 4); s += __shfl_xor(s, 8);
            float rs = 1.0f / s;
            int row = fm * 16 + r0 + r;
            Pw[row * 64 +  0 + fr] = f2bf(e0 * rs);
            Pw[row * 64 + 16 + fr] = f2bf(e1 * rs);
            Pw[row * 64 + 32 + fr] = f2bf(e2 * rs);
            Pw[row * 64 + 48 + fr] = f2bf(e3 * rs);
        }
    }

    f32x4 acc2[4][4];
    #pragma unroll
    for (int i = 0; i < 4; ++i)
        #pragma unroll
        for (int j = 0; j < 4; ++j) acc2[i][j] = (f32x4){0.f, 0.f, 0.f, 0.f};
    #pragma unroll
    for (int ks = 0; ks < 2; ++ks) {
        bf16x8 a[4], bb[4];
        #pragma unroll
        for (int fm = 0; fm < 4; ++fm)
            a[fm] = *(const bf16x8*)&Pw[(fm * 16 + fr) * 64 + ks * 32 + fk];
        #pragma unroll
        for (int fn = 0; fn < 4; ++fn)
            bb[fn] = *(const bf16x8*)&VT[(fn * 16 + fr) * 64 + ks * 32 + fk];
        #pragma unroll
        for (int fm = 0; fm < 4; ++fm)
            #pragma unroll
            for (int fn = 0; fn < 4; ++fn)
                acc2[fm][fn] = __builtin_amdgcn_mfma_f32_16x16x32_bf16(
                    a[fm], bb[fn], acc2[fm][fn], 0, 0, 0);
    }
    __syncthreads();

    u16* X2 = Qs;
    #pragma unroll
    for (int fm = 0; fm < 4; ++fm)
        #pragma unroll
        for (int fn = 0; fn < 4; ++fn)
            #pragma unroll
            for (int r = 0; r < 4; ++r)
                X2[(w * 64 + fm * 16 + r0 + r) * 64 + fn * 16 + fr] = f2bf(acc2[fm][fn][r]);
    __syncthreads();

    {
        const int d = t >> 2, cq = (t & 3) * 64;
        u16* orow = xsa + ((size_t)b * NN + d * 128 + h * 32 + nc) * 256 + cq;
        #pragma unroll
        for (int i = 0; i < 8; ++i) {
            bf16x8 v;
            #pragma unroll
            for (int j = 0; j < 8; ++j) v[j] = (short)X2[(cq + i * 8 + j) * 64 + d];
            *(bf16x8*)&orow[i * 8] = v;
        }
    }
}

// ---- shared GEMM body for out halves (R15 verified form) ----
__device__ __forceinline__ void out_gemm_body(
    const u16* __restrict__ A, const u16* __restrict__ Bt,
    const float* __restrict__ bias, int outoff, int m0,
    float* __restrict__ out, u16* As, u16* Bs, int t)
{
    const int lane = t & 63, w = t >> 6;
    const int wr = w >> 1, wc = w & 1;
    const int fr = lane & 15, fk = (lane >> 4) * 8, r0 = (lane >> 4) * 4;
    const int row0 = t >> 2, k80 = (t & 3) * 8;
    const int row1 = (256 + t) >> 2, k81 = ((256 + t) & 3) * 8;

    f32x4 acc[4][4];
    #pragma unroll
    for (int i = 0; i < 4; ++i)
        #pragma unroll
        for (int j = 0; j < 4; ++j) acc[i][j] = (f32x4){0.f, 0.f, 0.f, 0.f};

    for (int kt = 0; kt < 8; ++kt) {
        const int k0 = kt * 32;
        gl16(A  + (size_t)(m0 + row0) * 256 + k0 + k80, &As[t * 8]);
        gl16(A  + (size_t)(m0 + row1) * 256 + k0 + k81, &As[(256 + t) * 8]);
        gl16(Bt + (size_t)row0 * 256 + k0 + k80, &Bs[t * 8]);
        gl16(Bt + (size_t)row1 * 256 + k0 + k81, &Bs[(256 + t) * 8]);
        __syncthreads();
        bf16x8 a[4], bfr[4];
        #pragma unroll
        for (int fm = 0; fm < 4; ++fm)
            a[fm] = *(const bf16x8*)&As[(wr * 64 + fm * 16 + fr) * 32 + fk];
        #pragma unroll
        for (int fn = 0; fn < 4; ++fn)
            bfr[fn] = *(const bf16x8*)&Bs[(wc * 64 + fn * 16 + fr) * 32 + fk];
        #pragma unroll
        for (int fm = 0; fm < 4; ++fm)
            #pragma unroll
            for (int fn = 0; fn < 4; ++fn)
                acc[fm][fn] = __builtin_amdgcn_mfma_f32_16x16x32_bf16(
                    a[fm], bfr[fn], acc[fm][fn], 0, 0, 0);
        __syncthreads();
    }

    #pragma unroll
    for (int fm = 0; fm < 4; ++fm)
        #pragma unroll
        for (int fn = 0; fn < 4; ++fn) {
            int gcol = wc * 64 + fn * 16 + fr;
            #pragma unroll
            for (int r = 0; r < 4; ++r) {
                size_t grow = (size_t)(m0 + wr * 64 + fm * 16 + r0 + r);
                out[grow * 256 + outoff + gcol] = acc[fm][fn][r] + bias[gcol];
            }
        }
}

// ================= stage 5: mw2eff (512 blks) || outSA (256 blks) =================
__global__ __launch_bounds__(256) void mwout_kernel(
    const float* __restrict__ caprob, const float* __restrict__ Wo2,
    const float* __restrict__ Wvca, u16* __restrict__ W2effb,
    const u16* __restrict__ xsa, const u16* __restrict__ Wo1b,
    const float* __restrict__ bo1, float* __restrict__ out)
{
    __shared__ u16 sm[8192];
    const int t = threadIdx.x;
    if (blockIdx.x < 512) {
        float* Ml = (float*)sm;
        const int bj = blockIdx.x;
        const int b = bj >> 7, j = bj & 127;
        const int h = t >> 6, e = t & 63;
        float s = 0.f;
        #pragma unroll 8
        for (int d = 0; d < 64; ++d)
            s += Wo2[j * 256 + h * 64 + d] * caprob[(size_t)(b * 256 + h * 64 + d) * 64 + e];
        Ml[t] = s;
        __syncthreads();
        float s2 = 0.f;
        for (int c = 0; c < 256; ++c) s2 += Ml[c] * Wvca[c * 256 + t];
        W2effb[(size_t)bj * 256 + t] = f2bf(s2);
        return;
    }
    const int m0 = (blockIdx.x - 512) * 128;
    out_gemm_body(xsa, Wo1b, bo1, 0, m0, out, sm, sm + 4096, t);
}

// ================= stage 6: outCA (256 blks) =================
__global__ __launch_bounds__(256) void outca_kernel(
    const u16* __restrict__ xb, const u16* __restrict__ W2effb,
    const float* __restrict__ bo2, float* __restrict__ out)
{
    __shared__ u16 sm[8192];
    const int t = threadIdx.x;
    const int m0 = blockIdx.x * 128;
    const u16* Bt = W2effb + (size_t)(blockIdx.x >> 6) * 128 * 256;
    out_gemm_body(xb, Bt, bo2, 128, m0, out, sm, sm + 4096, t);
}

extern "C" void kernel_launch(void* const* d_in, const int* in_sizes, int n_in,
                              void* d_out, int out_size, void* d_ws, size_t ws_size,
                              hipStream_t stream) {
    float* out = (float*)d_out;

    static const int expect[14] = {8388608, 8388608, 65536, 65536, 65536, 65536,
                                   524288, 64, 4, 4, 32768, 128, 32768, 128};
    bool ok = (n_in == 14) && (out_size == 8388608);
    if (ok) for (int i = 0; i < 14; ++i) ok = ok && (in_sizes[i] == expect[i]);
    if (!ok) {
        fill_kernel<<<dim3(8192), 256, 0, stream>>>(out, 3000.0f);
        return;
    }
    if (ws_size < 80000000u) {
        fill_kernel<<<dim3(8192), 256, 0, stream>>>(out, 1000.0f);
        return;
    }

    const float* x    = (const float*)d_in[0];
    const float* q    = (const float*)d_in[1];
    const float* Wq   = (const float*)d_in[2];
    const float* Wk   = (const float*)d_in[3];
    const float* Wvca = (const float*)d_in[4];
    const float* Wvsa = (const float*)d_in[5];
    const float* Ew   = (const float*)d_in[6];
    const float* Eb   = (const float*)d_in[7];
    const float* temp = (const float*)d_in[8];
    const float* temp2= (const float*)d_in[9];
    const float* Wo1  = (const float*)d_in[10];
    const float* bo1  = (const float*)d_in[11];
    const float* Wo2  = (const float*)d_in[12];
    const float* bo2  = (const float*)d_in[13];

    u16* Qb   = (u16*)d_ws;
    u16* Kb   = Qb + (size_t)BNC;        // reused as xsa after calog (stream-ordered)
    u16* xb   = Kb + (size_t)BNC;
    u16* Wqb  = xb + (size_t)BNC;        // 65536
    u16* Wkb  = Wqb + 65536;             // 65536
    u16* Wo1b = Wkb + 65536;             // 32768
    u16* Ewb  = Wo1b + 32768;            // 524288
    u16* W2effb = Ewb + 524288;          // 131072
    u16* xsa  = Kb;
    float* fs    = (float*)(W2effb + 131072);
    float* nq2   = fs;                   // 1024
    float* nk2   = nq2 + 1024;           // 1024
    float* xE    = nk2 + 1024;           // 65536
    float* kp    = xE + 65536;           // 65536
    float* vp    = kp + 65536;           // 65536
    float* caprob= vp + 65536;           // 65536
    float* cpart = caprob + 65536;       // 1048576 (16 x 65536)

    zeroconv_kernel<<<dim3(4696), 256, 0, stream>>>(x, Wq, Wk, Wo1, Ew,
                                                    xb, Wqb, Wkb, Wo1b, Ewb, nq2);
    qkxe_kernel<<<dim3(1280), 256, 0, stream>>>(q, xb, Wqb, Wkb, Qb, Kb, nq2, nk2,
                                                Ewb, xE);
    calogkv_kernel<<<dim3(768), 256, 0, stream>>>(Qb, Kb, cpart, Wk, Wvsa, xE, Eb, kp, vp);
    smsa_kernel<<<dim3(768), 256, 0, stream>>>(cpart, nq2, nk2, temp, caprob,
                                               Qb, kp, vp, temp2, xsa);
    mwout_kernel<<<dim3(768), 256, 0, stream>>>(caprob, Wo2, Wvca, W2effb,
                                                xsa, Wo1b, bo1, out);
    outca_kernel<<<dim3(256), 256, 0, stream>>>(xb, W2effb, bo2, out);
}